// Round 6
// baseline (641.918 us; speedup 1.0000x reference)
//
#include <hip/hip_runtime.h>
#include <hip/hip_bf16.h>

using f32x4 = __attribute__((ext_vector_type(4))) float;
using bf16x8 = __attribute__((ext_vector_type(8))) short;

#define DEVI __device__ __forceinline__

DEVI short f2bf(float f) { __hip_bfloat16 h = __float2bfloat16(f); return *reinterpret_cast<short*>(&h); }
DEVI unsigned int pk2(float a, float b) {
    float2 t; t.x = a; t.y = b;
    __hip_bfloat162 h = __float22bfloat162_rn(t);
    return *reinterpret_cast<unsigned int*>(&h);
}
DEVI float bf2f(unsigned short s) { unsigned int u = ((unsigned int)s) << 16; return __uint_as_float(u); }

constexpr int NB = 8192;   // windows
constexpr int NT = 49;     // tokens per window
constexpr int CD = 128;    // channels
constexpr float SCALE = 0.17677669529663687f; // 32^-0.5
constexpr float LOG2E = 1.4426950408889634f;

// ---- ws layout (bytes) ----
constexpr size_t WS_QKVWT  = 0;        // 384*128 bf16 = 98304
constexpr size_t WS_PROJWT = 98304;    // 128*128 bf16 = 32768
constexpr size_t WS_BIAS   = 131072;   // 4*2401 bf16  = 19208
constexpr size_t WS_QKV    = 150528;   // 3 * 8192*4*49*32 bf16
constexpr size_t SQKV      = (size_t)NB * 4 * NT * 32;      // shorts per q/k/v plane
constexpr size_t WS_SPLIT_NEED = WS_QKV + 3 * SQKV * 2;     // ~308.4 MB

// row -> (window, token) exact divide by 49 (valid for n < 5.2e9)
DEVI void div49(unsigned grow, unsigned& bI, unsigned& tI) {
    bI = (unsigned)(((unsigned long long)grow * 2804876602ull) >> 37);
    tI = grow - bI * 49u;
}

__global__ __launch_bounds__(256) void prep_kernel(
    const float* __restrict__ qkv_w, const float* __restrict__ proj_w,
    const float* __restrict__ rbt, const int* __restrict__ rel_index,
    short* __restrict__ qkvwT, short* __restrict__ projwT, unsigned short* __restrict__ biasBf)
{
    int i = blockIdx.x * 256 + threadIdx.x;
    if (i < 384 * 128) { int j = i >> 7, k = i & 127; qkvwT[i] = f2bf(qkv_w[k * 384 + j]); }
    if (i < 128 * 128) { int j = i >> 7, k = i & 127; projwT[i] = f2bf(proj_w[k * 128 + j]); }
    if (i < 4 * NT * NT) { int h = i / (NT * NT); int t = i % (NT * NT); biasBf[i] = (unsigned short)f2bf(rbt[rel_index[t] * 4 + h]); }
}

// swizzled index into a [64][128] bf16 tile (fused fallback only)
DEVI int swz128(int row, int col) { return row * 128 + (col ^ ((row & 7) << 3)); }

// ============================================================================
// Kernel A: QKV GEMM -> qkv[s][b][h][t][d] bf16 (q pre-scaled).
// No global stores inside the MFMA loop: results go to an LDS tile (lgkm only),
// then one barrier + a fully-coalesced store pass (fire-and-forget dwordx4).
// grid = 401408/64 = 6272 blocks x 256 thr.
// ============================================================================
__global__ __launch_bounds__(256, 3) void qkv_gemm_kernel(
    const float* __restrict__ x, const float* __restrict__ qkv_b,
    const short* __restrict__ qkvwT, short* __restrict__ qkv)
{
    __shared__ short ot[64 * 392];   // 50176 B; stride 392 shorts = 784 B (16B-mult)

    const int tid = threadIdx.x;
    const int w = tid >> 6, lane = tid & 63, lr = lane & 15, lg = lane >> 4;
    const unsigned m0 = blockIdx.x * 64 + 16 * w;

    // A-fragments direct from global (independent, issued up-front)
    bf16x8 a[4];
    {
        const float* xrow = x + (size_t)(m0 + lr) * CD;
#pragma unroll
        for (int kt = 0; kt < 4; ++kt) {
            const float4* p = reinterpret_cast<const float4*>(xrow + kt * 32 + lg * 8);
            float4 v0 = p[0], v1 = p[1];
            union { unsigned int u[4]; bf16x8 v; } cv;
            cv.u[0] = pk2(v0.x, v0.y); cv.u[1] = pk2(v0.z, v0.w);
            cv.u[2] = pk2(v1.x, v1.y); cv.u[3] = pk2(v1.z, v1.w);
            a[kt] = cv.v;
        }
    }

#pragma unroll
    for (int nt = 0; nt < 24; ++nt) {
        f32x4 acc = {0.f, 0.f, 0.f, 0.f};
#pragma unroll
        for (int kt = 0; kt < 4; ++kt) {
            bf16x8 bb = *reinterpret_cast<const bf16x8*>(&qkvwT[(nt * 16 + lr) * 128 + kt * 32 + lg * 8]);
            acc = __builtin_amdgcn_mfma_f32_16x16x32_bf16(a[kt], bb, acc, 0, 0, 0);
        }
        const int col = nt * 16 + lr;                 // global qkv col 0..383
        const float bias = qkv_b[col];
        const float scl = (nt < 8) ? SCALE : 1.0f;    // s==0 -> q
#pragma unroll
        for (int r = 0; r < 4; ++r)
            ot[(16 * w + 4 * lg + r) * 392 + col] = f2bf((acc[r] + bias) * scl);
    }
    __syncthreads();

    // store pass: 12 (s,h) rounds; thread -> (row = tid/4, part = tid%4)
    {
        const int row = tid >> 2, part = tid & 3;
        unsigned bI, tI;
        div49(blockIdx.x * 64 + row, bI, tI);
        const size_t dbase = (size_t)bI * 6272 + (size_t)tI * 32 + part * 8;
#pragma unroll
        for (int sh = 0; sh < 12; ++sh) {
            int s = sh >> 2, h = sh & 3;
            bf16x8 vv = *reinterpret_cast<const bf16x8*>(&ot[row * 392 + s * 128 + h * 32 + part * 8]);
            *reinterpret_cast<bf16x8*>(qkv + (size_t)s * SQKV + dbase + h * 1568) = vv;
        }
    }
}

// ============================================================================
// Kernel B: attention only. block = (window, head-pair), 4 waves,
// wave = (local head, query-half). LDS 26624B -> 5-6 blocks/CU.
// Output o written IN-PLACE over the (dead) q plane, per-head layout.
// ============================================================================
__global__ __launch_bounds__(256, 5) void attn_kernel(
    short* __restrict__ qkv, const float* __restrict__ mask,
    const unsigned short* __restrict__ biasBf)
{
    __shared__ short pool[13312];     // P[2][64][72] (9216 sh) + vT[2][32][64] (4096 sh)
    short* P  = pool;
    short* vT = pool + 9216;

    const int b  = blockIdx.x >> 1, hp = blockIdx.x & 1;
    const int tid = threadIdx.x;
    const int w = tid >> 6, lane = tid & 63, lr = lane & 15, lg = lane >> 4;
    const int lh = w >> 1, half = w & 1;
    const int h = 2 * hp + lh;

    const size_t slice = (size_t)(b * 4 + h) * (NT * 32);
    short* qg = qkv + slice;                       // becomes o after reads
    const short* kg = qkv + SQKV + slice;
    const short* vg = qkv + 2 * SQKV + slice;
    short* vTl = vT + lh * 2048;
    short* Ph  = P + lh * 4608;

    // ---- Q/K fragments first (global loads issued early; rows>=49 read
    //      in-bounds finite garbage, masked in softmax) ----
    const int mt0 = 2 * half;
    bf16x8 qa[2], kb[4];
#pragma unroll
    for (int i = 0; i < 2; ++i)
        qa[i] = *reinterpret_cast<const bf16x8*>(qg + (16 * (mt0 + i) + lr) * 32 + lg * 8);
#pragma unroll
    for (int t4 = 0; t4 < 4; ++t4)
        kb[t4] = *reinterpret_cast<const bf16x8*>(kg + (16 * t4 + lr) * 32 + lg * 8);

    // ---- stage V (this wave: tokens [32*half, 32*half+32); slots>=49 zeroed) ----
    for (int i = lane; i < 32 * 8; i += 64) {      // 4 iters
        int tt = 32 * half + (i >> 3), d0 = (i & 7) * 4;
        short4 v4 = {0, 0, 0, 0};
        if (tt < NT) v4 = *reinterpret_cast<const short4*>(vg + tt * 32 + d0);
        vTl[(d0 + 0) * 64 + (tt ^ (((d0 + 0) & 7) << 3))] = v4.x;
        vTl[(d0 + 1) * 64 + (tt ^ (((d0 + 1) & 7) << 3))] = v4.y;
        vTl[(d0 + 2) * 64 + (tt ^ (((d0 + 2) & 7) << 3))] = v4.z;
        vTl[(d0 + 3) * 64 + (tt ^ (((d0 + 3) & 7) << 3))] = v4.w;
    }
    __syncthreads();   // #1: V staged; all q/k reads of this block precede this

    const float* maskb = mask + (size_t)b * (NT * NT);
    const unsigned short* biash = biasBf + h * (NT * NT);

    f32x4 oacc[2][2];
#pragma unroll
    for (int mt2 = 0; mt2 < 2; ++mt2) { oacc[mt2][0] = f32x4{0,0,0,0}; oacc[mt2][1] = f32x4{0,0,0,0}; }

#pragma unroll
    for (int mt2 = 0; mt2 < 2; ++mt2) {
        const int mt = mt0 + mt2;

        // prefetch mask AND bias for this tile (independent loads, issued early)
        float mreg[4][4], breg[4][4];
#pragma unroll
        for (int r = 0; r < 4; ++r) {
            int R = 16 * mt + 4 * lg + r;
#pragma unroll
            for (int ct = 0; ct < 4; ++ct) {
                int c = 16 * ct + lr;
                bool ok = (R < NT) && (c < NT);
                mreg[r][ct] = ok ? maskb[R * NT + c] : 0.f;
                breg[r][ct] = ok ? bf2f(biash[R * NT + c]) : 0.f;
            }
        }

        f32x4 sacc[4];
#pragma unroll
        for (int ct = 0; ct < 4; ++ct) {
            f32x4 z = {0.f, 0.f, 0.f, 0.f};
            sacc[ct] = __builtin_amdgcn_mfma_f32_16x16x32_bf16(qa[mt2], kb[ct], z, 0, 0, 0);
        }

        // softmax (no max-sub: valid logits bounded; padded rows/cols exact 0)
#pragma unroll
        for (int r = 0; r < 4; ++r) {
            int R = 16 * mt + 4 * lg + r;
            bool rv = R < NT;
            float e[4], sum;
#pragma unroll
            for (int ct = 0; ct < 4; ++ct) {
                int c = 16 * ct + lr;
                bool cv = c < NT;
                float sv = sacc[ct][r] + mreg[r][ct] + breg[r][ct];
                e[ct] = (rv && cv) ? exp2f(sv * LOG2E) : 0.f;
            }
            sum = (e[0] + e[1]) + (e[2] + e[3]);
            sum += __shfl_xor(sum, 1);
            sum += __shfl_xor(sum, 2);
            sum += __shfl_xor(sum, 4);
            sum += __shfl_xor(sum, 8);
            float inv = rv ? (1.0f / sum) : 0.f;
#pragma unroll
            for (int ct = 0; ct < 4; ++ct)
                Ph[R * 72 + 16 * ct + lr] = f2bf(e[ct] * inv);
        }

        // PV (own-wave P rows + own-head vT)
        bf16x8 pa0 = *reinterpret_cast<const bf16x8*>(&Ph[(16 * mt + lr) * 72 + lg * 8]);
        bf16x8 pa1 = *reinterpret_cast<const bf16x8*>(&Ph[(16 * mt + lr) * 72 + 32 + lg * 8]);
#pragma unroll
        for (int nt = 0; nt < 2; ++nt) {
            int dl = 16 * nt + lr;
            bf16x8 vb0 = *reinterpret_cast<const bf16x8*>(&vTl[dl * 64 + ((lg * 8) ^ ((dl & 7) << 3))]);
            bf16x8 vb1 = *reinterpret_cast<const bf16x8*>(&vTl[dl * 64 + ((32 + lg * 8) ^ ((dl & 7) << 3))]);
            oacc[mt2][nt] = __builtin_amdgcn_mfma_f32_16x16x32_bf16(pa0, vb0, oacc[mt2][nt], 0, 0, 0);
            oacc[mt2][nt] = __builtin_amdgcn_mfma_f32_16x16x32_bf16(pa1, vb1, oacc[mt2][nt], 0, 0, 0);
        }
    }

    // ---- o epilogue: overwrite own q plane [t][d] (fire-and-forget stores) ----
#pragma unroll
    for (int mt2 = 0; mt2 < 2; ++mt2)
#pragma unroll
        for (int nt = 0; nt < 2; ++nt)
#pragma unroll
            for (int r = 0; r < 4; ++r) {
                int R = 16 * (mt0 + mt2) + 4 * lg + r;
                if (R < NT)
                    qg[R * 32 + 16 * nt + lr] = f2bf(oacc[mt2][nt][r]);
            }
}

// ============================================================================
// Kernel C: proj GEMM. Reads o from the q planes ([b][h][t][d]), writes fp32 out.
// All accumulators in regs; global stores only in the epilogue.
// grid = 6272 x 256.
// ============================================================================
__global__ __launch_bounds__(256, 5) void proj_kernel(
    const short* __restrict__ qkv, const float* __restrict__ proj_b,
    const short* __restrict__ projwT, float* __restrict__ out)
{
    const int tid = threadIdx.x;
    const int w = tid >> 6, lane = tid & 63, lr = lane & 15, lg = lane >> 4;
    const unsigned m0 = blockIdx.x * 64 + 16 * w;

    // A-fragments: row m0+lr, cols kt*32.. = head kt slice of window's o
    bf16x8 a[4];
    {
        unsigned bI, tI;
        div49(m0 + lr, bI, tI);
        const short* obase = qkv + (size_t)bI * 6272 + (size_t)tI * 32 + lg * 8;
#pragma unroll
        for (int kt = 0; kt < 4; ++kt)
            a[kt] = *reinterpret_cast<const bf16x8*>(obase + kt * 1568);
    }

    f32x4 acc8[8];
#pragma unroll
    for (int nt = 0; nt < 8; ++nt) {
        f32x4 acc = {0.f, 0.f, 0.f, 0.f};
#pragma unroll
        for (int kt = 0; kt < 4; ++kt) {
            bf16x8 bb = *reinterpret_cast<const bf16x8*>(&projwT[(nt * 16 + lr) * 128 + kt * 32 + lg * 8]);
            acc = __builtin_amdgcn_mfma_f32_16x16x32_bf16(a[kt], bb, acc, 0, 0, 0);
        }
        acc8[nt] = acc;
    }

    // epilogue: 64B-segment stores, no loads after
#pragma unroll
    for (int nt = 0; nt < 8; ++nt) {
        int col = nt * 16 + lr;
        float pb = proj_b[col];
#pragma unroll
        for (int r = 0; r < 4; ++r) {
            unsigned grow = m0 + 4 * lg + r;
            out[(size_t)grow * CD + col] = acc8[nt][r] + pb;
        }
    }
}

// ============================================================================
// Fallback fused kernel (R3, known-passing) — used only if ws_size too small.
// ============================================================================
constexpr int QK_STRIDE = 72;
constexpr int QK_HEAD   = 64 * QK_STRIDE;
constexpr int VT_BASE   = 4 * QK_HEAD;
constexpr int POOL_SH   = VT_BASE + 4 * 32 * 64;

__global__ __launch_bounds__(512) void winattn_fused_kernel(
    const float* __restrict__ x, const float* __restrict__ mask,
    const float* __restrict__ qkv_b, const float* __restrict__ proj_b,
    const short* __restrict__ qkvwT, const short* __restrict__ projwT,
    const unsigned short* __restrict__ biasBf, float* __restrict__ out)
{
    __shared__ short pool[POOL_SH];
    short* qk = pool;
    short* vT = pool + VT_BASE;

    const int b = blockIdx.x;
    const int tid = threadIdx.x;
    const int w = tid >> 6;
    const int lane = tid & 63;
    const int lr = lane & 15;
    const int lg = lane >> 4;
    const int wr = w >> 1;
    const int wh = w & 1;

    bf16x8 a[4];
    {
        const int arow = 16 * wr + lr;
        const bool avalid = arow < NT;
        const float* xrow = x + (long)b * NT * CD + arow * CD;
#pragma unroll
        for (int kt = 0; kt < 4; ++kt) {
            float4 v0 = {0.f,0.f,0.f,0.f}, v1 = {0.f,0.f,0.f,0.f};
            if (avalid) {
                const float4* p = reinterpret_cast<const float4*>(xrow + kt * 32 + lg * 8);
                v0 = p[0]; v1 = p[1];
            }
            union { unsigned int u[4]; bf16x8 v; } cv;
            cv.u[0] = pk2(v0.x, v0.y); cv.u[1] = pk2(v0.z, v0.w);
            cv.u[2] = pk2(v1.x, v1.y); cv.u[3] = pk2(v1.z, v1.w);
            a[kt] = cv.v;
        }
    }
    {
        int nt0 = wh * 12;
#pragma unroll
        for (int i = 0; i < 12; ++i) {
            int nt = nt0 + i;
            f32x4 acc = {0.f, 0.f, 0.f, 0.f};
#pragma unroll
            for (int kt = 0; kt < 4; ++kt) {
                bf16x8 bb = *reinterpret_cast<const bf16x8*>(&qkvwT[(nt * 16 + lr) * 128 + kt * 32 + lg * 8]);
                acc = __builtin_amdgcn_mfma_f32_16x16x32_bf16(a[kt], bb, acc, 0, 0, 0);
            }
            int s = nt >> 3, hh = (nt >> 1) & 3, d = (nt & 1) * 16 + lr;
            float bias = qkv_b[nt * 16 + lr];
#pragma unroll
            for (int r = 0; r < 4; ++r) {
                int row = 16 * wr + 4 * lg + r;
                float vv = acc[r] + bias;
                if (s == 0)      qk[hh * QK_HEAD + row * QK_STRIDE + d] = f2bf(vv * SCALE);
                else if (s == 1) qk[hh * QK_HEAD + row * QK_STRIDE + 32 + d] = f2bf(vv);
                else             vT[hh * 2048 + d * 64 + (row ^ ((d & 7) << 3))] = f2bf(vv);
            }
        }
    }
    __syncthreads();
    {
        const int hh = wr;
        const int mt0 = wh * 2;
        short* qh = qk + hh * QK_HEAD;
        bf16x8 qa[2], kb[4];
#pragma unroll
        for (int t = 0; t < 2; ++t)
            qa[t] = *reinterpret_cast<const bf16x8*>(&qh[(16 * (mt0 + t) + lr) * QK_STRIDE + lg * 8]);
#pragma unroll
        for (int t = 0; t < 4; ++t)
            kb[t] = *reinterpret_cast<const bf16x8*>(&qh[(16 * t + lr) * QK_STRIDE + 32 + lg * 8]);
        __syncthreads();
        const float* maskb = mask + (long)b * NT * NT;
        const unsigned short* biash = biasBf + hh * NT * NT;
        f32x4 oacc[2][2];
#pragma unroll
        for (int mt2 = 0; mt2 < 2; ++mt2) { oacc[mt2][0] = f32x4{0,0,0,0}; oacc[mt2][1] = f32x4{0,0,0,0}; }
#pragma unroll
        for (int mt2 = 0; mt2 < 2; ++mt2) {
            const int mt = mt0 + mt2;
            float mreg[4][4];
#pragma unroll
            for (int r = 0; r < 4; ++r) {
                int R = 16 * mt + 4 * lg + r;
#pragma unroll
                for (int ct = 0; ct < 4; ++ct) {
                    int c = 16 * ct + lr;
                    mreg[r][ct] = (R < NT && c < NT) ? maskb[R * NT + c] : 0.f;
                }
            }
            f32x4 sacc[4];
#pragma unroll
            for (int ct = 0; ct < 4; ++ct) {
                f32x4 z = {0.f, 0.f, 0.f, 0.f};
                sacc[ct] = __builtin_amdgcn_mfma_f32_16x16x32_bf16(qa[mt2], kb[ct], z, 0, 0, 0);
            }
#pragma unroll
            for (int r = 0; r < 4; ++r) {
                int R = 16 * mt + 4 * lg + r;
                bool rv = R < NT;
                float e[4], sum;
#pragma unroll
                for (int ct = 0; ct < 4; ++ct) {
                    int c = 16 * ct + lr;
                    bool cvv = c < NT;
                    float bval = (rv && cvv) ? bf2f(biash[R * NT + c]) : 0.f;
                    float sv = sacc[ct][r] + mreg[r][ct] + bval;
                    e[ct] = (rv && cvv) ? exp2f(sv * LOG2E) : 0.f;
                }
                sum = (e[0] + e[1]) + (e[2] + e[3]);
                sum += __shfl_xor(sum, 1);
                sum += __shfl_xor(sum, 2);
                sum += __shfl_xor(sum, 4);
                sum += __shfl_xor(sum, 8);
                float inv = rv ? (1.0f / sum) : 0.f;
#pragma unroll
                for (int ct = 0; ct < 4; ++ct)
                    qh[R * QK_STRIDE + 16 * ct + lr] = f2bf(e[ct] * inv);
            }
            bf16x8 pa0 = *reinterpret_cast<const bf16x8*>(&qh[(16 * mt + lr) * QK_STRIDE + lg * 8]);
            bf16x8 pa1 = *reinterpret_cast<const bf16x8*>(&qh[(16 * mt + lr) * QK_STRIDE + 32 + lg * 8]);
#pragma unroll
            for (int nt = 0; nt < 2; ++nt) {
                int dl = 16 * nt + lr;
                bf16x8 vb0 = *reinterpret_cast<const bf16x8*>(&vT[hh * 2048 + dl * 64 + ((lg * 8) ^ ((dl & 7) << 3))]);
                bf16x8 vb1 = *reinterpret_cast<const bf16x8*>(&vT[hh * 2048 + dl * 64 + ((32 + lg * 8) ^ ((dl & 7) << 3))]);
                oacc[mt2][nt] = __builtin_amdgcn_mfma_f32_16x16x32_bf16(pa0, vb0, oacc[mt2][nt], 0, 0, 0);
                oacc[mt2][nt] = __builtin_amdgcn_mfma_f32_16x16x32_bf16(pa1, vb1, oacc[mt2][nt], 0, 0, 0);
            }
        }
        __syncthreads();
        short* o = vT;
#pragma unroll
        for (int mt2 = 0; mt2 < 2; ++mt2)
#pragma unroll
            for (int nt = 0; nt < 2; ++nt)
#pragma unroll
                for (int r = 0; r < 4; ++r)
                    o[swz128(16 * (mt0 + mt2) + 4 * lg + r, 32 * hh + 16 * nt + lr)] = f2bf(oacc[mt2][nt][r]);
    }
    __syncthreads();
    {
        const short* o = vT;
        bf16x8 ao[4];
#pragma unroll
        for (int kt = 0; kt < 4; ++kt)
            ao[kt] = *reinterpret_cast<const bf16x8*>(&o[swz128(16 * wr + lr, kt * 32 + lg * 8)]);
        int n0 = wh * 4;
#pragma unroll
        for (int i = 0; i < 4; ++i) {
            int nt = n0 + i;
            f32x4 acc = {0.f, 0.f, 0.f, 0.f};
#pragma unroll
            for (int kt = 0; kt < 4; ++kt) {
                bf16x8 bb = *reinterpret_cast<const bf16x8*>(&projwT[(nt * 16 + lr) * 128 + kt * 32 + lg * 8]);
                acc = __builtin_amdgcn_mfma_f32_16x16x32_bf16(ao[kt], bb, acc, 0, 0, 0);
            }
            int col = nt * 16 + lr;
            float pb = proj_b[col];
#pragma unroll
            for (int r = 0; r < 4; ++r) {
                int row = 16 * wr + 4 * lg + r;
                if (row < NT)
                    out[((long)b * NT + row) * CD + col] = acc[r] + pb;
            }
        }
    }
}

extern "C" void kernel_launch(void* const* d_in, const int* in_sizes, int n_in,
                              void* d_out, int out_size, void* d_ws, size_t ws_size,
                              hipStream_t stream) {
    const float* x      = (const float*)d_in[0];
    const float* mask   = (const float*)d_in[1];
    const float* qkv_w  = (const float*)d_in[2];
    const float* qkv_b  = (const float*)d_in[3];
    const float* rbt    = (const float*)d_in[4];
    const float* proj_w = (const float*)d_in[5];
    const float* proj_b = (const float*)d_in[6];
    const int*   ridx   = (const int*)d_in[7];
    float* out = (float*)d_out;

    char* ws = (char*)d_ws;
    short* qkvwT  = (short*)(ws + WS_QKVWT);
    short* projwT = (short*)(ws + WS_PROJWT);
    unsigned short* biasBf = (unsigned short*)(ws + WS_BIAS);

    prep_kernel<<<192, 256, 0, stream>>>(qkv_w, proj_w, rbt, ridx, qkvwT, projwT, biasBf);

    if (ws_size >= WS_SPLIT_NEED) {
        short* qkv = (short*)(ws + WS_QKV);
        qkv_gemm_kernel<<<(NB * NT) / 64, 256, 0, stream>>>(x, qkv_b, qkvwT, qkv);
        attn_kernel<<<NB * 2, 256, 0, stream>>>(qkv, mask, biasBf);
        proj_kernel<<<(NB * NT) / 64, 256, 0, stream>>>(qkv, proj_b, projwT, out);
    } else {
        winattn_fused_kernel<<<NB, 512, 0, stream>>>(x, mask, qkv_b, proj_b, qkvwT, projwT, biasBf, out);
    }
}

// Round 7
// 399.928 us; speedup vs baseline: 1.6051x; 1.6051x over previous
//
#include <hip/hip_runtime.h>
#include <hip/hip_bf16.h>

using f32x4 = __attribute__((ext_vector_type(4))) float;
using bf16x8 = __attribute__((ext_vector_type(8))) short;

#define DEVI __device__ __forceinline__

DEVI short f2bf(float f) { __hip_bfloat16 h = __float2bfloat16(f); return *reinterpret_cast<short*>(&h); }
DEVI unsigned int pk2(float a, float b) {
    float2 t; t.x = a; t.y = b;
    __hip_bfloat162 h = __float22bfloat162_rn(t);
    return *reinterpret_cast<unsigned int*>(&h);
}
DEVI float bf2f(unsigned short s) { unsigned int u = ((unsigned int)s) << 16; return __uint_as_float(u); }

// async global->LDS, 16B per lane (dest = wave-uniform base + lane*16)
#define GLOAD_LDS16(gp, lp) \
    __builtin_amdgcn_global_load_lds((const __attribute__((address_space(1))) void*)(gp), \
                                     (__attribute__((address_space(3))) void*)(lp), 16, 0, 0)

constexpr int NB = 8192;   // windows
constexpr int NT = 49;     // tokens per window
constexpr int CD = 128;    // channels
constexpr float SCALE = 0.17677669529663687f; // 32^-0.5
constexpr float LOG2E = 1.4426950408889634f;

// ---- ws layout (bytes) ----
constexpr size_t WS_QKVWT  = 0;        // 384*128 bf16 swizzled = 98304
constexpr size_t WS_PROJWT = 98304;    // 128*128 bf16 swizzled = 32768
constexpr size_t WS_BIAS   = 131072;   // 4*2401 bf16 = 19208
constexpr size_t WS_QKV    = 150528;   // 3 * 8192*4*49*32 bf16
constexpr size_t SQKV      = (size_t)NB * 4 * NT * 32;   // shorts per q/k/v plane

// row -> (window, token) exact divide by 49
DEVI void div49(unsigned grow, unsigned& bI, unsigned& tI) {
    bI = (unsigned)(((unsigned long long)grow * 2804876602ull) >> 37);
    tI = grow - bI * 49u;
}

// ============================================================================
// prep: weights -> bf16, transposed to B[n][k], PRE-SWIZZLED so that a linear
// global_load_lds copy yields LDS rows where element j of row r lives at
// j ^ ((r&7)<<3)  (byte XOR ((r&7)<<4)).  Bias gathered to [h][q][k] bf16.
// ============================================================================
__global__ __launch_bounds__(256) void prep_kernel(
    const float* __restrict__ qkv_w, const float* __restrict__ proj_w,
    const float* __restrict__ rbt, const int* __restrict__ rel_index,
    short* __restrict__ qkvwS, short* __restrict__ projwS, unsigned short* __restrict__ biasBf)
{
    int i = blockIdx.x * 256 + threadIdx.x;
    if (i < 384 * 128) {
        int n = i >> 7, j = i & 127;          // B[n][k=j]
        int c = n >> 7, r = n & 127;
        qkvwS[c * 16384 + r * 128 + (j ^ ((r & 7) << 3))] = f2bf(qkv_w[j * 384 + n]);
    }
    if (i < 128 * 128) {
        int n = i >> 7, j = i & 127;
        qkvwS[0] = qkvwS[0];                  // no-op keep
        projwS[n * 128 + (j ^ ((n & 7) << 3))] = f2bf(proj_w[j * 128 + n]);
    }
    if (i < 4 * NT * NT) {
        int h = i / (NT * NT); int t = i % (NT * NT);
        biasBf[i] = (unsigned short)f2bf(rbt[rel_index[t] * 4 + h]);
    }
}

// ============================================================================
// Kernel A: QKV GEMM (M=401408, N=384, K=128) -> qkv[s][b][h][t][d], q scaled.
// Block = 128 rows x full N, 4 waves (wave: 2 M-frags of 16 rows).
// B staged per 128-col chunk in LDS (32KB) via global_load_lds; ds_read_b128
// with XOR swizzle (conflict-free); MFMA loop has no global dependencies.
// grid = 3136.
// ============================================================================
__global__ __launch_bounds__(256, 2) void qkv_gemm_kernel(
    const float* __restrict__ x, const float* __restrict__ qkv_b,
    const short* __restrict__ qkvwS, short* __restrict__ qkv)
{
    __shared__ short ldsB[16384];   // 32 KB: [128 rows][128 cols] swizzled
    const int tid = threadIdx.x;
    const int w = tid >> 6, lane = tid & 63, lr = lane & 15, lg = lane >> 4;
    const unsigned m0 = blockIdx.x * 128 + w * 32;

    // ---- A-fragments (2 M-frags x 4 kt) direct from global fp32 ----
    bf16x8 af[2][4];
#pragma unroll
    for (int mf = 0; mf < 2; ++mf) {
        const float* xrow = x + (size_t)(m0 + mf * 16 + lr) * CD;
#pragma unroll
        for (int kt = 0; kt < 4; ++kt) {
            const float4* p = reinterpret_cast<const float4*>(xrow + kt * 32 + lg * 8);
            float4 v0 = p[0], v1 = p[1];
            union { unsigned int u[4]; bf16x8 v; } cv;
            cv.u[0] = pk2(v0.x, v0.y); cv.u[1] = pk2(v0.z, v0.w);
            cv.u[2] = pk2(v1.x, v1.y); cv.u[3] = pk2(v1.z, v1.w);
            af[mf][kt] = cv.v;
        }
    }

    // ---- per-(mf,r) store row offsets ----
    unsigned rowoff[2][4];
#pragma unroll
    for (int mf = 0; mf < 2; ++mf)
#pragma unroll
        for (int r = 0; r < 4; ++r) {
            unsigned bI, tI;
            div49(m0 + mf * 16 + 4 * lg + r, bI, tI);
            rowoff[mf][r] = bI * 6272u + tI * 32u;
        }

    const char* srcB = (const char*)qkvwS;
    char* ldsBc = (char*)ldsB;

#pragma unroll
    for (int c = 0; c < 3; ++c) {
        // stage B chunk c: 32KB, 8 x 1KB per wave
#pragma unroll
        for (int i = 0; i < 8; ++i)
            GLOAD_LDS16(srcB + c * 32768 + w * 8192 + i * 1024 + lane * 16,
                        ldsBc + w * 8192 + i * 1024);
        __syncthreads();   // compiler drains vmcnt before barrier

        f32x4 acc[2][8];
#pragma unroll
        for (int mf = 0; mf < 2; ++mf)
#pragma unroll
            for (int n = 0; n < 8; ++n) acc[mf][n] = f32x4{0.f, 0.f, 0.f, 0.f};

#pragma unroll
        for (int ntl = 0; ntl < 8; ++ntl) {
            const int rrow = ntl * 16 + lr;
            const char* rbase = ldsBc + rrow * 256;
            const int sw = (lr & 7) << 4;
#pragma unroll
            for (int kt = 0; kt < 4; ++kt) {
                bf16x8 bb = *reinterpret_cast<const bf16x8*>(rbase + ((kt * 64 + lg * 16) ^ sw));
                acc[0][ntl] = __builtin_amdgcn_mfma_f32_16x16x32_bf16(af[0][kt], bb, acc[0][ntl], 0, 0, 0);
                acc[1][ntl] = __builtin_amdgcn_mfma_f32_16x16x32_bf16(af[1][kt], bb, acc[1][ntl], 0, 0, 0);
            }
        }

        // epilogue: bias + (q) scale + scattered bf16 stores (32B segments)
        const float scl = (c == 0) ? SCALE : 1.0f;
        short* dplane = qkv + (size_t)c * SQKV;
#pragma unroll
        for (int ntl = 0; ntl < 8; ++ntl) {
            const int h = ntl >> 1;
            const int d = (ntl & 1) * 16 + lr;
            const float bias = qkv_b[c * 128 + ntl * 16 + lr];
#pragma unroll
            for (int mf = 0; mf < 2; ++mf)
#pragma unroll
                for (int r = 0; r < 4; ++r)
                    dplane[rowoff[mf][r] + h * 1568 + d] = f2bf((acc[mf][ntl][r] + bias) * scl);
        }
        __syncthreads();   // all ds_reads of chunk c done before restage
    }
}

// ============================================================================
// Kernel B: attention only (unchanged from R6). block = (window, head-pair),
// 4 waves, wave = (local head, query-half). o overwrites the dead q plane.
// ============================================================================
__global__ __launch_bounds__(256, 5) void attn_kernel(
    short* __restrict__ qkv, const float* __restrict__ mask,
    const unsigned short* __restrict__ biasBf)
{
    __shared__ short pool[13312];     // P[2][64][72] + vT[2][32][64]
    short* P  = pool;
    short* vT = pool + 9216;

    const int b  = blockIdx.x >> 1, hp = blockIdx.x & 1;
    const int tid = threadIdx.x;
    const int w = tid >> 6, lane = tid & 63, lr = lane & 15, lg = lane >> 4;
    const int lh = w >> 1, half = w & 1;
    const int h = 2 * hp + lh;

    const size_t slice = (size_t)(b * 4 + h) * (NT * 32);
    short* qg = qkv + slice;
    const short* kg = qkv + SQKV + slice;
    const short* vg = qkv + 2 * SQKV + slice;
    short* vTl = vT + lh * 2048;
    short* Ph  = P + lh * 4608;

    const int mt0 = 2 * half;
    bf16x8 qa[2], kb[4];
#pragma unroll
    for (int i = 0; i < 2; ++i)
        qa[i] = *reinterpret_cast<const bf16x8*>(qg + (16 * (mt0 + i) + lr) * 32 + lg * 8);
#pragma unroll
    for (int t4 = 0; t4 < 4; ++t4)
        kb[t4] = *reinterpret_cast<const bf16x8*>(kg + (16 * t4 + lr) * 32 + lg * 8);

    for (int i = lane; i < 32 * 8; i += 64) {
        int tt = 32 * half + (i >> 3), d0 = (i & 7) * 4;
        short4 v4 = {0, 0, 0, 0};
        if (tt < NT) v4 = *reinterpret_cast<const short4*>(vg + tt * 32 + d0);
        vTl[(d0 + 0) * 64 + (tt ^ (((d0 + 0) & 7) << 3))] = v4.x;
        vTl[(d0 + 1) * 64 + (tt ^ (((d0 + 1) & 7) << 3))] = v4.y;
        vTl[(d0 + 2) * 64 + (tt ^ (((d0 + 2) & 7) << 3))] = v4.z;
        vTl[(d0 + 3) * 64 + (tt ^ (((d0 + 3) & 7) << 3))] = v4.w;
    }
    __syncthreads();

    const float* maskb = mask + (size_t)b * (NT * NT);
    const unsigned short* biash = biasBf + h * (NT * NT);

    f32x4 oacc[2][2];
#pragma unroll
    for (int mt2 = 0; mt2 < 2; ++mt2) { oacc[mt2][0] = f32x4{0,0,0,0}; oacc[mt2][1] = f32x4{0,0,0,0}; }

#pragma unroll
    for (int mt2 = 0; mt2 < 2; ++mt2) {
        const int mt = mt0 + mt2;
        float mreg[4][4], breg[4][4];
#pragma unroll
        for (int r = 0; r < 4; ++r) {
            int R = 16 * mt + 4 * lg + r;
#pragma unroll
            for (int ct = 0; ct < 4; ++ct) {
                int c = 16 * ct + lr;
                bool ok = (R < NT) && (c < NT);
                mreg[r][ct] = ok ? maskb[R * NT + c] : 0.f;
                breg[r][ct] = ok ? bf2f(biash[R * NT + c]) : 0.f;
            }
        }

        f32x4 sacc[4];
#pragma unroll
        for (int ct = 0; ct < 4; ++ct) {
            f32x4 z = {0.f, 0.f, 0.f, 0.f};
            sacc[ct] = __builtin_amdgcn_mfma_f32_16x16x32_bf16(qa[mt2], kb[ct], z, 0, 0, 0);
        }

#pragma unroll
        for (int r = 0; r < 4; ++r) {
            int R = 16 * mt + 4 * lg + r;
            bool rv = R < NT;
            float e[4], sum;
#pragma unroll
            for (int ct = 0; ct < 4; ++ct) {
                int c = 16 * ct + lr;
                bool cv = c < NT;
                float sv = sacc[ct][r] + mreg[r][ct] + breg[r][ct];
                e[ct] = (rv && cv) ? exp2f(sv * LOG2E) : 0.f;
            }
            sum = (e[0] + e[1]) + (e[2] + e[3]);
            sum += __shfl_xor(sum, 1);
            sum += __shfl_xor(sum, 2);
            sum += __shfl_xor(sum, 4);
            sum += __shfl_xor(sum, 8);
            float inv = rv ? (1.0f / sum) : 0.f;
#pragma unroll
            for (int ct = 0; ct < 4; ++ct)
                Ph[R * 72 + 16 * ct + lr] = f2bf(e[ct] * inv);
        }

        bf16x8 pa0 = *reinterpret_cast<const bf16x8*>(&Ph[(16 * mt + lr) * 72 + lg * 8]);
        bf16x8 pa1 = *reinterpret_cast<const bf16x8*>(&Ph[(16 * mt + lr) * 72 + 32 + lg * 8]);
#pragma unroll
        for (int nt = 0; nt < 2; ++nt) {
            int dl = 16 * nt + lr;
            bf16x8 vb0 = *reinterpret_cast<const bf16x8*>(&vTl[dl * 64 + ((lg * 8) ^ ((dl & 7) << 3))]);
            bf16x8 vb1 = *reinterpret_cast<const bf16x8*>(&vTl[dl * 64 + ((32 + lg * 8) ^ ((dl & 7) << 3))]);
            oacc[mt2][nt] = __builtin_amdgcn_mfma_f32_16x16x32_bf16(pa0, vb0, oacc[mt2][nt], 0, 0, 0);
            oacc[mt2][nt] = __builtin_amdgcn_mfma_f32_16x16x32_bf16(pa1, vb1, oacc[mt2][nt], 0, 0, 0);
        }
    }

#pragma unroll
    for (int mt2 = 0; mt2 < 2; ++mt2)
#pragma unroll
        for (int nt = 0; nt < 2; ++nt)
#pragma unroll
            for (int r = 0; r < 4; ++r) {
                int R = 16 * (mt0 + mt2) + 4 * lg + r;
                if (R < NT)
                    qg[R * 32 + 16 * nt + lr] = f2bf(oacc[mt2][nt][r]);
            }
}

// ============================================================================
// Kernel C: proj GEMM (M=401408, N=128, K=128). o read from the q planes,
// B = projwS staged in LDS (same recipe as A). fp32 coalesced stores.
// grid = 3136.
// ============================================================================
__global__ __launch_bounds__(256, 2) void proj_kernel(
    const short* __restrict__ qkv, const float* __restrict__ proj_b,
    const short* __restrict__ projwS, float* __restrict__ out)
{
    __shared__ short ldsB[16384];   // 32 KB
    const int tid = threadIdx.x;
    const int w = tid >> 6, lane = tid & 63, lr = lane & 15, lg = lane >> 4;
    const unsigned m0 = blockIdx.x * 128 + w * 32;

    // stage B (issued first; A-loads overlap the DMA)
    const char* srcB = (const char*)projwS;
    char* ldsBc = (char*)ldsB;
#pragma unroll
    for (int i = 0; i < 8; ++i)
        GLOAD_LDS16(srcB + w * 8192 + i * 1024 + lane * 16, ldsBc + w * 8192 + i * 1024);

    // A-fragments from o ([b][h][t][d] in q plane)
    bf16x8 af[2][4];
#pragma unroll
    for (int mf = 0; mf < 2; ++mf) {
        unsigned bI, tI;
        div49(m0 + mf * 16 + lr, bI, tI);
        const short* obase = qkv + (size_t)bI * 6272 + (size_t)tI * 32 + lg * 8;
#pragma unroll
        for (int kt = 0; kt < 4; ++kt)
            af[mf][kt] = *reinterpret_cast<const bf16x8*>(obase + kt * 1568);
    }
    __syncthreads();

    f32x4 acc[2][8];
#pragma unroll
    for (int mf = 0; mf < 2; ++mf)
#pragma unroll
        for (int n = 0; n < 8; ++n) acc[mf][n] = f32x4{0.f, 0.f, 0.f, 0.f};

#pragma unroll
    for (int ntl = 0; ntl < 8; ++ntl) {
        const int rrow = ntl * 16 + lr;
        const char* rbase = ldsBc + rrow * 256;
        const int sw = (lr & 7) << 4;
#pragma unroll
        for (int kt = 0; kt < 4; ++kt) {
            bf16x8 bb = *reinterpret_cast<const bf16x8*>(rbase + ((kt * 64 + lg * 16) ^ sw));
            acc[0][ntl] = __builtin_amdgcn_mfma_f32_16x16x32_bf16(af[0][kt], bb, acc[0][ntl], 0, 0, 0);
            acc[1][ntl] = __builtin_amdgcn_mfma_f32_16x16x32_bf16(af[1][kt], bb, acc[1][ntl], 0, 0, 0);
        }
    }

    // epilogue: fp32 stores, 64B segments
#pragma unroll
    for (int mf = 0; mf < 2; ++mf) {
        const size_t gr0 = (size_t)(m0 + mf * 16 + 4 * lg) * CD;
#pragma unroll
        for (int ntl = 0; ntl < 8; ++ntl) {
            int col = ntl * 16 + lr;
            float pb = proj_b[col];
#pragma unroll
            for (int r = 0; r < 4; ++r)
                out[gr0 + (size_t)r * CD + col] = acc[mf][ntl][r] + pb;
        }
    }
}

extern "C" void kernel_launch(void* const* d_in, const int* in_sizes, int n_in,
                              void* d_out, int out_size, void* d_ws, size_t ws_size,
                              hipStream_t stream) {
    const float* x      = (const float*)d_in[0];
    const float* mask   = (const float*)d_in[1];
    const float* qkv_w  = (const float*)d_in[2];
    const float* qkv_b  = (const float*)d_in[3];
    const float* rbt    = (const float*)d_in[4];
    const float* proj_w = (const float*)d_in[5];
    const float* proj_b = (const float*)d_in[6];
    const int*   ridx   = (const int*)d_in[7];
    float* out = (float*)d_out;

    char* ws = (char*)d_ws;
    short* qkvwS  = (short*)(ws + WS_QKVWT);
    short* projwS = (short*)(ws + WS_PROJWT);
    unsigned short* biasBf = (unsigned short*)(ws + WS_BIAS);
    short* qkv = (short*)(ws + WS_QKV);

    prep_kernel<<<192, 256, 0, stream>>>(qkv_w, proj_w, rbt, ridx, qkvwS, projwS, biasBf);
    qkv_gemm_kernel<<<(NB * NT) / 128, 256, 0, stream>>>(x, qkv_b, qkvwS, qkv);
    attn_kernel<<<NB * 2, 256, 0, stream>>>(qkv, mask, biasBf);
    proj_kernel<<<(NB * NT) / 128, 256, 0, stream>>>(qkv, proj_b, projwS, out);
}

// Round 8
// 392.165 us; speedup vs baseline: 1.6369x; 1.0198x over previous
//
#include <hip/hip_runtime.h>
#include <hip/hip_bf16.h>

using f32x4 = __attribute__((ext_vector_type(4))) float;
using bf16x8 = __attribute__((ext_vector_type(8))) short;

#define DEVI __device__ __forceinline__

DEVI short f2bf(float f) { __hip_bfloat16 h = __float2bfloat16(f); return *reinterpret_cast<short*>(&h); }
DEVI unsigned int pk2(float a, float b) {
    float2 t; t.x = a; t.y = b;
    __hip_bfloat162 h = __float22bfloat162_rn(t);
    return *reinterpret_cast<unsigned int*>(&h);
}
DEVI float bf2f(unsigned short s) { unsigned int u = ((unsigned int)s) << 16; return __uint_as_float(u); }

// async global->LDS, 16B per lane (dest = wave-uniform base + lane*16)
#define GLOAD_LDS16(gp, lp) \
    __builtin_amdgcn_global_load_lds((const __attribute__((address_space(1))) void*)(gp), \
                                     (__attribute__((address_space(3))) void*)(lp), 16, 0, 0)

constexpr int NB = 8192;   // windows
constexpr int NT = 49;     // tokens per window
constexpr int CD = 128;    // channels
constexpr float SCALE = 0.17677669529663687f; // 32^-0.5
constexpr float LOG2E = 1.4426950408889634f;

// ---- ws layout (bytes) ----
constexpr size_t WS_QKVWT  = 0;        // 384*128 bf16 swizzled = 98304
constexpr size_t WS_PROJWT = 98304;    // 128*128 bf16 swizzled = 32768
constexpr size_t WS_BIAS   = 131072;   // 4*2401 bf16 = 19208 (pre-multiplied by LOG2E)
constexpr size_t WS_QKV    = 150528;   // 3 * 8192*4*49*32 bf16
constexpr size_t SQKV      = (size_t)NB * 4 * NT * 32;   // shorts per q/k/v plane

// row -> (window, token) exact divide by 49
DEVI void div49(unsigned grow, unsigned& bI, unsigned& tI) {
    bI = (unsigned)(((unsigned long long)grow * 2804876602ull) >> 37);
    tI = grow - bI * 49u;
}

// ============================================================================
// prep: weights -> bf16, transposed to B[n][k], PRE-SWIZZLED for linear
// global_load_lds + XOR ds_read. Bias gathered to [h][q][k] bf16, x LOG2E.
// ============================================================================
__global__ __launch_bounds__(256) void prep_kernel(
    const float* __restrict__ qkv_w, const float* __restrict__ proj_w,
    const float* __restrict__ rbt, const int* __restrict__ rel_index,
    short* __restrict__ qkvwS, short* __restrict__ projwS, unsigned short* __restrict__ biasBf)
{
    int i = blockIdx.x * 256 + threadIdx.x;
    if (i < 384 * 128) {
        int n = i >> 7, j = i & 127;          // B[n][k=j]
        int c = n >> 7, r = n & 127;
        qkvwS[c * 16384 + r * 128 + (j ^ ((r & 7) << 3))] = f2bf(qkv_w[j * 384 + n]);
    }
    if (i < 128 * 128) {
        int n = i >> 7, j = i & 127;
        projwS[n * 128 + (j ^ ((n & 7) << 3))] = f2bf(proj_w[j * 128 + n]);
    }
    if (i < 4 * NT * NT) {
        int h = i / (NT * NT); int t = i % (NT * NT);
        biasBf[i] = (unsigned short)f2bf(rbt[rel_index[t] * 4 + h] * LOG2E);
    }
}

// ============================================================================
// Kernel A: QKV GEMM (M=401408, N=384, K=128) -> qkv[s][b][h][t][d].
// q pre-scaled by SCALE*LOG2E (softmax works in exp2 domain).
// ============================================================================
__global__ __launch_bounds__(256, 2) void qkv_gemm_kernel(
    const float* __restrict__ x, const float* __restrict__ qkv_b,
    const short* __restrict__ qkvwS, short* __restrict__ qkv)
{
    __shared__ short ldsB[16384];   // 32 KB: [128 rows][128 cols] swizzled
    const int tid = threadIdx.x;
    const int w = tid >> 6, lane = tid & 63, lr = lane & 15, lg = lane >> 4;
    const unsigned m0 = blockIdx.x * 128 + w * 32;

    bf16x8 af[2][4];
#pragma unroll
    for (int mf = 0; mf < 2; ++mf) {
        const float* xrow = x + (size_t)(m0 + mf * 16 + lr) * CD;
#pragma unroll
        for (int kt = 0; kt < 4; ++kt) {
            const float4* p = reinterpret_cast<const float4*>(xrow + kt * 32 + lg * 8);
            float4 v0 = p[0], v1 = p[1];
            union { unsigned int u[4]; bf16x8 v; } cv;
            cv.u[0] = pk2(v0.x, v0.y); cv.u[1] = pk2(v0.z, v0.w);
            cv.u[2] = pk2(v1.x, v1.y); cv.u[3] = pk2(v1.z, v1.w);
            af[mf][kt] = cv.v;
        }
    }

    unsigned rowoff[2][4];
#pragma unroll
    for (int mf = 0; mf < 2; ++mf)
#pragma unroll
        for (int r = 0; r < 4; ++r) {
            unsigned bI, tI;
            div49(m0 + mf * 16 + 4 * lg + r, bI, tI);
            rowoff[mf][r] = bI * 6272u + tI * 32u;
        }

    const char* srcB = (const char*)qkvwS;
    char* ldsBc = (char*)ldsB;

#pragma unroll
    for (int c = 0; c < 3; ++c) {
#pragma unroll
        for (int i = 0; i < 8; ++i)
            GLOAD_LDS16(srcB + c * 32768 + w * 8192 + i * 1024 + lane * 16,
                        ldsBc + w * 8192 + i * 1024);
        __syncthreads();

        f32x4 acc[2][8];
#pragma unroll
        for (int mf = 0; mf < 2; ++mf)
#pragma unroll
            for (int n = 0; n < 8; ++n) acc[mf][n] = f32x4{0.f, 0.f, 0.f, 0.f};

#pragma unroll
        for (int ntl = 0; ntl < 8; ++ntl) {
            const int rrow = ntl * 16 + lr;
            const char* rbase = ldsBc + rrow * 256;
            const int sw = (lr & 7) << 4;
#pragma unroll
            for (int kt = 0; kt < 4; ++kt) {
                bf16x8 bb = *reinterpret_cast<const bf16x8*>(rbase + ((kt * 64 + lg * 16) ^ sw));
                acc[0][ntl] = __builtin_amdgcn_mfma_f32_16x16x32_bf16(af[0][kt], bb, acc[0][ntl], 0, 0, 0);
                acc[1][ntl] = __builtin_amdgcn_mfma_f32_16x16x32_bf16(af[1][kt], bb, acc[1][ntl], 0, 0, 0);
            }
        }

        const float scl = (c == 0) ? SCALE * LOG2E : 1.0f;
        short* dplane = qkv + (size_t)c * SQKV;
#pragma unroll
        for (int ntl = 0; ntl < 8; ++ntl) {
            const int h = ntl >> 1;
            const int d = (ntl & 1) * 16 + lr;
            const float bias = qkv_b[c * 128 + ntl * 16 + lr];
#pragma unroll
            for (int mf = 0; mf < 2; ++mf)
#pragma unroll
                for (int r = 0; r < 4; ++r)
                    dplane[rowoff[mf][r] + h * 1568 + d] = f2bf((acc[mf][ntl][r] + bias) * scl);
        }
        __syncthreads();
    }
}

// ============================================================================
// Kernel B: attention. block = window (512 thr, 8 waves), wave = (head, half).
// Mask staged once per block into zero-padded LDS [50][68] fp32 (x LOG2E);
// bias via imm-offset unpredicated loads; only ct=3 needs a column mask
// (c=16ct+lr<49 is compile-time true for ct<3). P unnormalized; o scaled by
// inv at epilogue. o overwrites the dead q plane.
// LDS: mask 13600 + P 36864 + vT 16384 = 66848 B -> 2 blocks/CU.
// ============================================================================
__global__ __launch_bounds__(512, 4) void attn_kernel(
    short* __restrict__ qkv, const float* __restrict__ mask,
    const unsigned short* __restrict__ biasBf)
{
    __shared__ float mlds[50 * 68];            // stride 68: uniform 2-way banks
    __shared__ short pool[18432 + 8192];       // P[4][64][72] + vT[4][32][64]
    short* P  = pool;
    short* vT = pool + 18432;

    const int b = blockIdx.x;
    const int tid = threadIdx.x;
    const int w = tid >> 6, lane = tid & 63, lr = lane & 15, lg = lane >> 4;
    const int h = w >> 1, half = w & 1;

    const size_t slice = (size_t)(b * 4 + h) * (NT * 32);
    short* qg = qkv + slice;                   // becomes o after reads
    const short* kg = qkv + SQKV + slice;
    const short* vg = qkv + 2 * SQKV + slice;
    short* vTl = vT + h * 2048;
    short* Ph  = P + h * 4608;

    // ---- Q/K fragment loads first (longest-latency, independent) ----
    const int mt0 = 2 * half;
    bf16x8 qa[2], kb[4];
#pragma unroll
    for (int i = 0; i < 2; ++i)
        qa[i] = *reinterpret_cast<const bf16x8*>(qg + (16 * (mt0 + i) + lr) * 32 + lg * 8);
#pragma unroll
    for (int t4 = 0; t4 < 4; ++t4)
        kb[t4] = *reinterpret_cast<const bf16x8*>(kg + (16 * t4 + lr) * 32 + lg * 8);

    // ---- stage V (own head, own 32-token half; slots >=49 zeroed) ----
    for (int i = lane; i < 256; i += 64) {
        int tt = 32 * half + (i >> 3), d0 = (i & 7) * 4;
        short4 v4 = {0, 0, 0, 0};
        if (tt < NT) v4 = *reinterpret_cast<const short4*>(vg + tt * 32 + d0);
        vTl[(d0 + 0) * 64 + (tt ^ (((d0 + 0) & 7) << 3))] = v4.x;
        vTl[(d0 + 1) * 64 + (tt ^ (((d0 + 1) & 7) << 3))] = v4.y;
        vTl[(d0 + 2) * 64 + (tt ^ (((d0 + 2) & 7) << 3))] = v4.z;
        vTl[(d0 + 3) * 64 + (tt ^ (((d0 + 3) & 7) << 3))] = v4.w;
    }

    // ---- stage mask x LOG2E into zero-padded [50][68] (single pass) ----
    {
        const float* mb = mask + (size_t)b * (NT * NT);
        for (int i = tid; i < 50 * 68; i += 512) {
            int row = i / 68;
            int col = i - row * 68;
            float v = 0.f;
            if (row < NT && col < NT) v = mb[row * NT + col] * LOG2E;
            mlds[i] = v;
        }
    }
    __syncthreads();

    const unsigned short* biash = biasBf + h * (NT * NT);

    f32x4 oacc[2][2];
#pragma unroll
    for (int mt2 = 0; mt2 < 2; ++mt2) { oacc[mt2][0] = f32x4{0,0,0,0}; oacc[mt2][1] = f32x4{0,0,0,0}; }
    float inv[2][4];

#pragma unroll
    for (int mt2 = 0; mt2 < 2; ++mt2) {
        const int mt = mt0 + mt2;

        f32x4 sacc[4];
#pragma unroll
        for (int ct = 0; ct < 4; ++ct) {
            f32x4 z = {0.f, 0.f, 0.f, 0.f};
            sacc[ct] = __builtin_amdgcn_mfma_f32_16x16x32_bf16(qa[mt2], kb[ct], z, 0, 0, 0);
        }

        // one bias base per mt2; per-(r,ct) reads at compile-time offsets
        const unsigned short* bb = biash + (16 * mt + 4 * lg) * NT + lr;

#pragma unroll
        for (int r = 0; r < 4; ++r) {
            const int R = 16 * mt + 4 * lg + r;
            const float* mrow = mlds + min(R, 49) * 68 + lr;   // clamped row; pads are 0
            float e[4];
#pragma unroll
            for (int ct = 0; ct < 4; ++ct) {
                float sv = sacc[ct][r] + mrow[ct * 16] + bf2f(bb[r * NT + ct * 16]);
                float ee = exp2f(sv);
                // c = 16*ct + lr < 49 always for ct<3; ct==3 valid only when lr==0
                e[ct] = (ct < 3 || lr == 0) ? ee : 0.f;
            }
            float sum = (e[0] + e[1]) + (e[2] + e[3]);
            sum += __shfl_xor(sum, 1);
            sum += __shfl_xor(sum, 2);
            sum += __shfl_xor(sum, 4);
            sum += __shfl_xor(sum, 8);
            inv[mt2][r] = 1.0f / sum;
#pragma unroll
            for (int ct = 0; ct < 4; ++ct)
                Ph[R * 72 + 16 * ct + lr] = f2bf(e[ct]);       // unnormalized (masked) P
        }

        // PV (own-wave P rows + own-head vT)
        bf16x8 pa0 = *reinterpret_cast<const bf16x8*>(&Ph[(16 * mt + lr) * 72 + lg * 8]);
        bf16x8 pa1 = *reinterpret_cast<const bf16x8*>(&Ph[(16 * mt + lr) * 72 + 32 + lg * 8]);
#pragma unroll
        for (int nt = 0; nt < 2; ++nt) {
            int dl = 16 * nt + lr;
            bf16x8 vb0 = *reinterpret_cast<const bf16x8*>(&vTl[dl * 64 + ((lg * 8) ^ ((dl & 7) << 3))]);
            bf16x8 vb1 = *reinterpret_cast<const bf16x8*>(&vTl[dl * 64 + ((32 + lg * 8) ^ ((dl & 7) << 3))]);
            oacc[mt2][nt] = __builtin_amdgcn_mfma_f32_16x16x32_bf16(pa0, vb0, oacc[mt2][nt], 0, 0, 0);
            oacc[mt2][nt] = __builtin_amdgcn_mfma_f32_16x16x32_bf16(pa1, vb1, oacc[mt2][nt], 0, 0, 0);
        }
    }

    // ---- o epilogue: normalize by inv and overwrite own q plane ----
#pragma unroll
    for (int mt2 = 0; mt2 < 2; ++mt2)
#pragma unroll
        for (int nt = 0; nt < 2; ++nt)
#pragma unroll
            for (int r = 0; r < 4; ++r) {
                int R = 16 * (mt0 + mt2) + 4 * lg + r;
                if (R < NT)
                    qg[R * 32 + 16 * nt + lr] = f2bf(oacc[mt2][nt][r] * inv[mt2][r]);
            }
}

// ============================================================================
// Kernel C: proj GEMM (M=401408, N=128, K=128). Reads o from the q planes.
// ============================================================================
__global__ __launch_bounds__(256, 2) void proj_kernel(
    const short* __restrict__ qkv, const float* __restrict__ proj_b,
    const short* __restrict__ projwS, float* __restrict__ out)
{
    __shared__ short ldsB[16384];
    const int tid = threadIdx.x;
    const int w = tid >> 6, lane = tid & 63, lr = lane & 15, lg = lane >> 4;
    const unsigned m0 = blockIdx.x * 128 + w * 32;

    const char* srcB = (const char*)projwS;
    char* ldsBc = (char*)ldsB;
#pragma unroll
    for (int i = 0; i < 8; ++i)
        GLOAD_LDS16(srcB + w * 8192 + i * 1024 + lane * 16, ldsBc + w * 8192 + i * 1024);

    bf16x8 af[2][4];
#pragma unroll
    for (int mf = 0; mf < 2; ++mf) {
        unsigned bI, tI;
        div49(m0 + mf * 16 + lr, bI, tI);
        const short* obase = qkv + (size_t)bI * 6272 + (size_t)tI * 32 + lg * 8;
#pragma unroll
        for (int kt = 0; kt < 4; ++kt)
            af[mf][kt] = *reinterpret_cast<const bf16x8*>(obase + kt * 1568);
    }
    __syncthreads();

    f32x4 acc[2][8];
#pragma unroll
    for (int mf = 0; mf < 2; ++mf)
#pragma unroll
        for (int n = 0; n < 8; ++n) acc[mf][n] = f32x4{0.f, 0.f, 0.f, 0.f};

#pragma unroll
    for (int ntl = 0; ntl < 8; ++ntl) {
        const int rrow = ntl * 16 + lr;
        const char* rbase = ldsBc + rrow * 256;
        const int sw = (lr & 7) << 4;
#pragma unroll
        for (int kt = 0; kt < 4; ++kt) {
            bf16x8 bb = *reinterpret_cast<const bf16x8*>(rbase + ((kt * 64 + lg * 16) ^ sw));
            acc[0][ntl] = __builtin_amdgcn_mfma_f32_16x16x32_bf16(af[0][kt], bb, acc[0][ntl], 0, 0, 0);
            acc[1][ntl] = __builtin_amdgcn_mfma_f32_16x16x32_bf16(af[1][kt], bb, acc[1][ntl], 0, 0, 0);
        }
    }

#pragma unroll
    for (int mf = 0; mf < 2; ++mf) {
        const size_t gr0 = (size_t)(m0 + mf * 16 + 4 * lg) * CD;
#pragma unroll
        for (int ntl = 0; ntl < 8; ++ntl) {
            int col = ntl * 16 + lr;
            float pb = proj_b[col];
#pragma unroll
            for (int r = 0; r < 4; ++r)
                out[gr0 + (size_t)r * CD + col] = acc[mf][ntl][r] + pb;
        }
    }
}

extern "C" void kernel_launch(void* const* d_in, const int* in_sizes, int n_in,
                              void* d_out, int out_size, void* d_ws, size_t ws_size,
                              hipStream_t stream) {
    const float* x      = (const float*)d_in[0];
    const float* mask   = (const float*)d_in[1];
    const float* qkv_w  = (const float*)d_in[2];
    const float* qkv_b  = (const float*)d_in[3];
    const float* rbt    = (const float*)d_in[4];
    const float* proj_w = (const float*)d_in[5];
    const float* proj_b = (const float*)d_in[6];
    const int*   ridx   = (const int*)d_in[7];
    float* out = (float*)d_out;

    char* ws = (char*)d_ws;
    short* qkvwS  = (short*)(ws + WS_QKVWT);
    short* projwS = (short*)(ws + WS_PROJWT);
    unsigned short* biasBf = (unsigned short*)(ws + WS_BIAS);
    short* qkv = (short*)(ws + WS_QKV);

    prep_kernel<<<192, 256, 0, stream>>>(qkv_w, proj_w, rbt, ridx, qkvwS, projwS, biasBf);
    qkv_gemm_kernel<<<(NB * NT) / 128, 256, 0, stream>>>(x, qkv_b, qkvwS, qkv);
    attn_kernel<<<NB, 512, 0, stream>>>(qkv, mask, biasBf);
    proj_kernel<<<(NB * NT) / 128, 256, 0, stream>>>(qkv, proj_b, projwS, out);
}

// Round 9
// 375.562 us; speedup vs baseline: 1.7092x; 1.0442x over previous
//
#include <hip/hip_runtime.h>
#include <hip/hip_bf16.h>

using f32x4 = __attribute__((ext_vector_type(4))) float;
using bf16x8 = __attribute__((ext_vector_type(8))) short;

#define DEVI __device__ __forceinline__

DEVI short f2bf(float f) { __hip_bfloat16 h = __float2bfloat16(f); return *reinterpret_cast<short*>(&h); }
DEVI unsigned int pk2(float a, float b) {
    float2 t; t.x = a; t.y = b;
    __hip_bfloat162 h = __float22bfloat162_rn(t);
    return *reinterpret_cast<unsigned int*>(&h);
}
DEVI float bf2f(unsigned short s) { unsigned int u = ((unsigned int)s) << 16; return __uint_as_float(u); }

// gfx950 cross-lane-group swaps (both operands modified):
// permlane32_swap: dst lanes 32-63 <-> src lanes 0-31
// permlane16_swap: dst lanes 16-31 <-> src lanes 0-15, dst 48-63 <-> src 32-47
DEVI void pl32swap(unsigned& a, unsigned& b) { asm("v_permlane32_swap_b32 %0, %1" : "+v"(a), "+v"(b)); }
DEVI void pl16swap(unsigned& a, unsigned& b) { asm("v_permlane16_swap_b32 %0, %1" : "+v"(a), "+v"(b)); }

// async global->LDS, 16B per lane (dest = wave-uniform base + lane*16)
#define GLOAD_LDS16(gp, lp) \
    __builtin_amdgcn_global_load_lds((const __attribute__((address_space(1))) void*)(gp), \
                                     (__attribute__((address_space(3))) void*)(lp), 16, 0, 0)

constexpr int NB = 8192;   // windows
constexpr int NT = 49;     // tokens per window
constexpr int CD = 128;    // channels
constexpr float SCALE = 0.17677669529663687f; // 32^-0.5
constexpr float LOG2E = 1.4426950408889634f;

// ---- ws layout (bytes) ----
constexpr size_t WS_QKVWT  = 0;        // 384*128 bf16 swizzled = 98304
constexpr size_t WS_PROJWT = 98304;    // 128*128 bf16 swizzled = 32768
constexpr size_t WS_BIAS   = 131072;   // 4*2401 bf16 transposed [h][k][q] x LOG2E
constexpr size_t WS_QKV    = 150528;   // 3 * 8192*4*49*32 bf16
constexpr size_t SQKV      = (size_t)NB * 4 * NT * 32;   // shorts per q/k/v plane

// row -> (window, token) exact divide by 49
DEVI void div49(unsigned grow, unsigned& bI, unsigned& tI) {
    bI = (unsigned)(((unsigned long long)grow * 2804876602ull) >> 37);
    tI = grow - bI * 49u;
}

// ============================================================================
// prep: weights transposed+pre-swizzled; bias gathered TRANSPOSED [h][k][q],
// pre-multiplied by LOG2E.
// ============================================================================
__global__ __launch_bounds__(256) void prep_kernel(
    const float* __restrict__ qkv_w, const float* __restrict__ proj_w,
    const float* __restrict__ rbt, const int* __restrict__ rel_index,
    short* __restrict__ qkvwS, short* __restrict__ projwS, unsigned short* __restrict__ biasBf)
{
    int i = blockIdx.x * 256 + threadIdx.x;
    if (i < 384 * 128) {
        int n = i >> 7, j = i & 127;          // B[n][k=j]
        int c = n >> 7, r = n & 127;
        qkvwS[c * 16384 + r * 128 + (j ^ ((r & 7) << 3))] = f2bf(qkv_w[j * 384 + n]);
    }
    if (i < 128 * 128) {
        int n = i >> 7, j = i & 127;
        projwS[n * 128 + (j ^ ((n & 7) << 3))] = f2bf(proj_w[j * 128 + n]);
    }
    if (i < 4 * NT * NT) {
        int h = i / (NT * NT); int t = i % (NT * NT);
        int k = t / NT, q = t - k * NT;       // dest index t = k*49 + q
        biasBf[i] = (unsigned short)f2bf(rbt[rel_index[q * NT + k] * 4 + h] * LOG2E);
    }
}

// ============================================================================
// Kernel A: QKV GEMM (M=401408, N=384, K=128) -> qkv[s][b][h][t][d].
// q pre-scaled by SCALE*LOG2E. (unchanged from R8)
// ============================================================================
__global__ __launch_bounds__(256, 2) void qkv_gemm_kernel(
    const float* __restrict__ x, const float* __restrict__ qkv_b,
    const short* __restrict__ qkvwS, short* __restrict__ qkv)
{
    __shared__ short ldsB[16384];
    const int tid = threadIdx.x;
    const int w = tid >> 6, lane = tid & 63, lr = lane & 15, lg = lane >> 4;
    const unsigned m0 = blockIdx.x * 128 + w * 32;

    bf16x8 af[2][4];
#pragma unroll
    for (int mf = 0; mf < 2; ++mf) {
        const float* xrow = x + (size_t)(m0 + mf * 16 + lr) * CD;
#pragma unroll
        for (int kt = 0; kt < 4; ++kt) {
            const float4* p = reinterpret_cast<const float4*>(xrow + kt * 32 + lg * 8);
            float4 v0 = p[0], v1 = p[1];
            union { unsigned int u[4]; bf16x8 v; } cv;
            cv.u[0] = pk2(v0.x, v0.y); cv.u[1] = pk2(v0.z, v0.w);
            cv.u[2] = pk2(v1.x, v1.y); cv.u[3] = pk2(v1.z, v1.w);
            af[mf][kt] = cv.v;
        }
    }

    unsigned rowoff[2][4];
#pragma unroll
    for (int mf = 0; mf < 2; ++mf)
#pragma unroll
        for (int r = 0; r < 4; ++r) {
            unsigned bI, tI;
            div49(m0 + mf * 16 + 4 * lg + r, bI, tI);
            rowoff[mf][r] = bI * 6272u + tI * 32u;
        }

    const char* srcB = (const char*)qkvwS;
    char* ldsBc = (char*)ldsB;

#pragma unroll
    for (int c = 0; c < 3; ++c) {
#pragma unroll
        for (int i = 0; i < 8; ++i)
            GLOAD_LDS16(srcB + c * 32768 + w * 8192 + i * 1024 + lane * 16,
                        ldsBc + w * 8192 + i * 1024);
        __syncthreads();

        f32x4 acc[2][8];
#pragma unroll
        for (int mf = 0; mf < 2; ++mf)
#pragma unroll
            for (int n = 0; n < 8; ++n) acc[mf][n] = f32x4{0.f, 0.f, 0.f, 0.f};

#pragma unroll
        for (int ntl = 0; ntl < 8; ++ntl) {
            const int rrow = ntl * 16 + lr;
            const char* rbase = ldsBc + rrow * 256;
            const int sw = (lr & 7) << 4;
#pragma unroll
            for (int kt = 0; kt < 4; ++kt) {
                bf16x8 bb = *reinterpret_cast<const bf16x8*>(rbase + ((kt * 64 + lg * 16) ^ sw));
                acc[0][ntl] = __builtin_amdgcn_mfma_f32_16x16x32_bf16(af[0][kt], bb, acc[0][ntl], 0, 0, 0);
                acc[1][ntl] = __builtin_amdgcn_mfma_f32_16x16x32_bf16(af[1][kt], bb, acc[1][ntl], 0, 0, 0);
            }
        }

        const float scl = (c == 0) ? SCALE * LOG2E : 1.0f;
        short* dplane = qkv + (size_t)c * SQKV;
#pragma unroll
        for (int ntl = 0; ntl < 8; ++ntl) {
            const int h = ntl >> 1;
            const int d = (ntl & 1) * 16 + lr;
            const float bias = qkv_b[c * 128 + ntl * 16 + lr];
#pragma unroll
            for (int mf = 0; mf < 2; ++mf)
#pragma unroll
                for (int r = 0; r < 4; ++r)
                    dplane[rowoff[mf][r] + h * 1568 + d] = f2bf((acc[mf][ntl][r] + bias) * scl);
        }
        __syncthreads();
    }
}

// ============================================================================
// Kernel B: attention, swapped-QK^T in-register softmax.
//   block = window (512 thr, 8 waves), wave = (head, query-half).
//   sacc = mfma(K, Q) -> lane holds S[k=16ct+4lg+r][q=16mt+lr]:
//     row-sum = 15 local adds + 2 shfl; inv lane-local; P = e*inv in regs.
//   P -> PV A-frag via cvt_pk + permlane16/32_swap butterfly; V staged in LDS
//   with matching slot-permuted columns. No P in LDS, no scattered P writes.
//   o overwrites the dead q plane. LDS = mask^T 13.6KB + V 16KB = 29.6KB.
// ============================================================================
__global__ __launch_bounds__(512, 4) void attn_kernel(
    short* __restrict__ qkv, const float* __restrict__ mask,
    const unsigned short* __restrict__ biasT)
{
    __shared__ float mT[50 * 68];          // transposed mask x LOG2E, zero-padded
    __shared__ short vS[4][2048];          // V, slot-layout cols, XOR-swizzled

    const int b = blockIdx.x;
    const int tid = threadIdx.x;
    const int w = tid >> 6, lane = tid & 63, lr = lane & 15, lg = lane >> 4;
    const int h = w >> 1, half = w & 1;

    const size_t slice = (size_t)(b * 4 + h) * (NT * 32);
    short* qg = qkv + slice;               // becomes o after reads
    const short* kg = qkv + SQKV + slice;
    const short* vg = qkv + 2 * SQKV + slice;
    short* vSl = vS[h];

    // ---- Q (2 tiles) / K (4 tiles) fragments, direct from global ----
    const int mt0 = 2 * half;
    bf16x8 qa[2], kb[4];
#pragma unroll
    for (int i = 0; i < 2; ++i)
        qa[i] = *reinterpret_cast<const bf16x8*>(qg + (16 * (mt0 + i) + lr) * 32 + lg * 8);
#pragma unroll
    for (int t4 = 0; t4 < 4; ++t4)
        kb[t4] = *reinterpret_cast<const bf16x8*>(kg + (16 * t4 + lr) * 32 + lg * 8);

    // ---- stage V into slot-permuted cols (tokens of own half; >=49 zeroed).
    // slot col for token tt=16a+bb: bb<8 -> 8a+bb (mfma k-block 0), else 24+8a+bb.
    for (int i = lane; i < 256; i += 64) {
        int tt = 32 * half + (i >> 3), d0 = (i & 7) * 4;
        short4 v4 = {0, 0, 0, 0};
        if (tt < NT) v4 = *reinterpret_cast<const short4*>(vg + tt * 32 + d0);
        int a = tt >> 4, bb2 = tt & 15;
        int col = (bb2 < 8) ? (a * 8 + bb2) : (24 + a * 8 + bb2);
        vSl[(d0 + 0) * 64 + (col ^ (((d0 + 0) & 7) << 3))] = v4.x;
        vSl[(d0 + 1) * 64 + (col ^ (((d0 + 1) & 7) << 3))] = v4.y;
        vSl[(d0 + 2) * 64 + (col ^ (((d0 + 2) & 7) << 3))] = v4.z;
        vSl[(d0 + 3) * 64 + (col ^ (((d0 + 3) & 7) << 3))] = v4.w;
    }
    // ---- zero mT, then fill transposed (coalesced global reads) ----
    for (int i = tid; i < 50 * 68; i += 512) mT[i] = 0.f;
    __syncthreads();
    {
        const float* mb_ = mask + (size_t)b * (NT * NT);
        for (int i = tid; i < NT * NT; i += 512) {
            unsigned q_, k_;
            div49((unsigned)i, q_, k_);        // i = q*49 + k
            mT[k_ * 68 + q_] = mb_[i] * LOG2E;
        }
    }
    __syncthreads();

    // ---- hoisted V fragments (mt-independent) ----
    bf16x8 vb[2][2];
    const int sw8 = (lr & 7) << 3;
#pragma unroll
    for (int nt = 0; nt < 2; ++nt)
#pragma unroll
        for (int blk = 0; blk < 2; ++blk)
            vb[nt][blk] = *reinterpret_cast<const bf16x8*>(
                &vSl[(16 * nt + lr) * 64 + ((blk * 32 + 8 * lg) ^ sw8)]);

    const unsigned short* biasTh = biasT + h * (NT * NT);

    f32x4 oacc[2][2];
#pragma unroll
    for (int mt2 = 0; mt2 < 2; ++mt2) { oacc[mt2][0] = f32x4{0,0,0,0}; oacc[mt2][1] = f32x4{0,0,0,0}; }

#pragma unroll
    for (int mt2 = 0; mt2 < 2; ++mt2) {
        const int mt = mt0 + mt2;
        const int qcol = 16 * mt + lr;

        // mask+bias prefetch: k-rows, q along lanes (conflict-free / coalesced)
        float mb[4][4];
#pragma unroll
        for (int ct = 0; ct < 4; ++ct)
#pragma unroll
            for (int r = 0; r < 4; ++r) {
                int k = 16 * ct + 4 * lg + r;
                int kc = min(k, 49);           // row 49 of mT is zeros
                mb[ct][r] = mT[kc * 68 + qcol] + bf2f(biasTh[kc * NT + qcol]);
            }

        // swapped QK^T: sacc[ct][r] = S[k=16ct+4lg+r][q=16mt+lr]
        f32x4 sacc[4];
#pragma unroll
        for (int ct = 0; ct < 4; ++ct) {
            f32x4 z = {0.f, 0.f, 0.f, 0.f};
            sacc[ct] = __builtin_amdgcn_mfma_f32_16x16x32_bf16(kb[ct], qa[mt2], z, 0, 0, 0);
        }

        // exp2 + lane-local row sum (k=48 is the only valid ct=3 slot)
        float e[4][4];
        float psum = 0.f;
#pragma unroll
        for (int ct = 0; ct < 4; ++ct)
#pragma unroll
            for (int r = 0; r < 4; ++r) {
                float ee = exp2f(sacc[ct][r] + mb[ct][r]);
                if (ct == 3) ee = (r == 0 && lg == 0) ? ee : 0.f;
                e[ct][r] = ee;
                psum += ee;
            }
        psum += __shfl_xor(psum, 16);
        psum += __shfl_xor(psum, 32);
        const float inv = 1.0f / psum;

        // P = e*inv packed to bf16x2 words; butterfly to PV A-frag layout.
        // A_ct = k+{0,1}, B_ct = k+{2,3} at k=16ct+4lg. After swaps:
        // A_ct' @group g' = rows k=16g'+4ct+{0,1} (B: +{2,3}).
        unsigned A0 = pk2(e[0][0] * inv, e[0][1] * inv);
        unsigned A1 = pk2(e[1][0] * inv, e[1][1] * inv);
        unsigned A2 = pk2(e[2][0] * inv, e[2][1] * inv);
        unsigned A3 = pk2(e[3][0] * inv, e[3][1] * inv);
        unsigned B0 = pk2(e[0][2] * inv, e[0][3] * inv);
        unsigned B1 = pk2(e[1][2] * inv, e[1][3] * inv);
        unsigned B2 = pk2(e[2][2] * inv, e[2][3] * inv);
        unsigned B3 = pk2(e[3][2] * inv, e[3][3] * inv);
        pl32swap(A0, A2); pl32swap(A1, A3);
        pl16swap(A0, A1); pl16swap(A2, A3);
        pl32swap(B0, B2); pl32swap(B1, B3);
        pl16swap(B0, B1); pl16swap(B2, B3);
        union { unsigned u[4]; bf16x8 v; } p0, p1;
        p0.u[0] = A0; p0.u[1] = B0; p0.u[2] = A1; p0.u[3] = B1;  // k=16g'+0..7
        p1.u[0] = A2; p1.u[1] = B2; p1.u[2] = A3; p1.u[3] = B3;  // k=16g'+8..15

        // PV: all-register A-operand, hoisted V fragments
#pragma unroll
        for (int nt = 0; nt < 2; ++nt) {
            oacc[mt2][nt] = __builtin_amdgcn_mfma_f32_16x16x32_bf16(p0.v, vb[nt][0], oacc[mt2][nt], 0, 0, 0);
            oacc[mt2][nt] = __builtin_amdgcn_mfma_f32_16x16x32_bf16(p1.v, vb[nt][1], oacc[mt2][nt], 0, 0, 0);
        }
    }

    // ---- o epilogue: overwrite own q plane [t][d] (normalization already in P)
#pragma unroll
    for (int mt2 = 0; mt2 < 2; ++mt2)
#pragma unroll
        for (int nt = 0; nt < 2; ++nt)
#pragma unroll
            for (int r = 0; r < 4; ++r) {
                int R = 16 * (mt0 + mt2) + 4 * lg + r;
                if (R < NT)
                    qg[R * 32 + 16 * nt + lr] = f2bf(oacc[mt2][nt][r]);
            }
}

// ============================================================================
// Kernel C: proj GEMM (M=401408, N=128, K=128). (unchanged from R8)
// ============================================================================
__global__ __launch_bounds__(256, 2) void proj_kernel(
    const short* __restrict__ qkv, const float* __restrict__ proj_b,
    const short* __restrict__ projwS, float* __restrict__ out)
{
    __shared__ short ldsB[16384];
    const int tid = threadIdx.x;
    const int w = tid >> 6, lane = tid & 63, lr = lane & 15, lg = lane >> 4;
    const unsigned m0 = blockIdx.x * 128 + w * 32;

    const char* srcB = (const char*)projwS;
    char* ldsBc = (char*)ldsB;
#pragma unroll
    for (int i = 0; i < 8; ++i)
        GLOAD_LDS16(srcB + w * 8192 + i * 1024 + lane * 16, ldsBc + w * 8192 + i * 1024);

    bf16x8 af[2][4];
#pragma unroll
    for (int mf = 0; mf < 2; ++mf) {
        unsigned bI, tI;
        div49(m0 + mf * 16 + lr, bI, tI);
        const short* obase = qkv + (size_t)bI * 6272 + (size_t)tI * 32 + lg * 8;
#pragma unroll
        for (int kt = 0; kt < 4; ++kt)
            af[mf][kt] = *reinterpret_cast<const bf16x8*>(obase + kt * 1568);
    }
    __syncthreads();

    f32x4 acc[2][8];
#pragma unroll
    for (int mf = 0; mf < 2; ++mf)
#pragma unroll
        for (int n = 0; n < 8; ++n) acc[mf][n] = f32x4{0.f, 0.f, 0.f, 0.f};

#pragma unroll
    for (int ntl = 0; ntl < 8; ++ntl) {
        const int rrow = ntl * 16 + lr;
        const char* rbase = ldsBc + rrow * 256;
        const int sw = (lr & 7) << 4;
#pragma unroll
        for (int kt = 0; kt < 4; ++kt) {
            bf16x8 bb = *reinterpret_cast<const bf16x8*>(rbase + ((kt * 64 + lg * 16) ^ sw));
            acc[0][ntl] = __builtin_amdgcn_mfma_f32_16x16x32_bf16(af[0][kt], bb, acc[0][ntl], 0, 0, 0);
            acc[1][ntl] = __builtin_amdgcn_mfma_f32_16x16x32_bf16(af[1][kt], bb, acc[1][ntl], 0, 0, 0);
        }
    }

#pragma unroll
    for (int mf = 0; mf < 2; ++mf) {
        const size_t gr0 = (size_t)(m0 + mf * 16 + 4 * lg) * CD;
#pragma unroll
        for (int ntl = 0; ntl < 8; ++ntl) {
            int col = ntl * 16 + lr;
            float pb = proj_b[col];
#pragma unroll
            for (int r = 0; r < 4; ++r)
                out[gr0 + (size_t)r * CD + col] = acc[mf][ntl][r] + pb;
        }
    }
}

extern "C" void kernel_launch(void* const* d_in, const int* in_sizes, int n_in,
                              void* d_out, int out_size, void* d_ws, size_t ws_size,
                              hipStream_t stream) {
    const float* x      = (const float*)d_in[0];
    const float* mask   = (const float*)d_in[1];
    const float* qkv_w  = (const float*)d_in[2];
    const float* qkv_b  = (const float*)d_in[3];
    const float* rbt    = (const float*)d_in[4];
    const float* proj_w = (const float*)d_in[5];
    const float* proj_b = (const float*)d_in[6];
    const int*   ridx   = (const int*)d_in[7];
    float* out = (float*)d_out;

    char* ws = (char*)d_ws;
    short* qkvwS  = (short*)(ws + WS_QKVWT);
    short* projwS = (short*)(ws + WS_PROJWT);
    unsigned short* biasBf = (unsigned short*)(ws + WS_BIAS);
    short* qkv = (short*)(ws + WS_QKV);

    prep_kernel<<<192, 256, 0, stream>>>(qkv_w, proj_w, rbt, ridx, qkvwS, projwS, biasBf);
    qkv_gemm_kernel<<<(NB * NT) / 128, 256, 0, stream>>>(x, qkv_b, qkvwS, qkv);
    attn_kernel<<<NB, 512, 0, stream>>>(qkv, mask, biasBf);
    proj_kernel<<<(NB * NT) / 128, 256, 0, stream>>>(qkv, proj_b, projwS, out);
}